// Round 12
// baseline (541.150 us; speedup 1.0000x reference)
//
#include <hip/hip_runtime.h>
#include <math.h>

#define HID 256
#define TD 32
#define NL 3
#define C1DIM 128
#define OUTDIM 2
#define QKVW 768

using half8  = __attribute__((ext_vector_type(8))) _Float16;
using half4v = __attribute__((ext_vector_type(4))) _Float16;
using half2v = __attribute__((ext_vector_type(2))) _Float16;
using f32x4  = __attribute__((ext_vector_type(4))) float;

typedef __attribute__((address_space(1))) void gbl_void_t;
typedef __attribute__((address_space(3))) void lds_void_t;

__device__ __forceinline__ void load16_to_lds(const void* g, void* l) {
  __builtin_amdgcn_global_load_lds((const gbl_void_t*)g, (lds_void_t*)l, 16, 0, 0);
}

__device__ __forceinline__ float dot8h(half8 a, half8 b, float acc) {
#if __has_builtin(__builtin_amdgcn_fdot2)
  union { half8 v; half2v h2[4]; } ua, ub;
  ua.v = a; ub.v = b;
#pragma unroll
  for (int j = 0; j < 4; ++j) acc = __builtin_amdgcn_fdot2(ua.h2[j], ub.h2[j], acc, false);
  return acc;
#else
#pragma unroll
  for (int j = 0; j < 8; ++j) acc += (float)a[j] * (float)b[j];
  return acc;
#endif
}

// ---------- merged: per-block ts min/max + time enc + x cvt + deg zero ----------
__global__ __launch_bounds__(256) void k_enc(const float* __restrict__ ts,
                                             const float* __restrict__ freq,
                                             const float* __restrict__ x,
                                             _Float16* __restrict__ tfh,
                                             _Float16* __restrict__ xh,
                                             int* __restrict__ deg, int n) {
  float lmin = INFINITY, lmax = -INFINITY;
  for (int i = threadIdx.x; i < n; i += 256) {
    float v = ts[i];
    lmin = fminf(lmin, v); lmax = fmaxf(lmax, v);
  }
#pragma unroll
  for (int off = 32; off >= 1; off >>= 1) {
    lmin = fminf(lmin, __shfl_xor(lmin, off));
    lmax = fmaxf(lmax, __shfl_xor(lmax, off));
  }
  __shared__ float wmin[4], wmax[4];
  int lane = threadIdx.x & 63, w = threadIdx.x >> 6;
  if (lane == 0) { wmin[w] = lmin; wmax[w] = lmax; }
  __syncthreads();
  float tmin = fminf(fminf(wmin[0], wmin[1]), fminf(wmin[2], wmin[3]));
  float tmax = fmaxf(fmaxf(wmax[0], wmax[1]), fmaxf(wmax[2], wmax[3]));
  float inv = 1.f / (tmax - tmin + 1e-8f);
  int nt = n * TD;
  int total = n * 64;
  for (int idx = blockIdx.x * 256 + threadIdx.x; idx < total; idx += gridDim.x * 256) {
    if (idx < nt) {
      int node = idx >> 5, j = idx & 31;
      float t = (ts[node] - tmin) * inv;
      float wv = t * freq[j & 15];
      tfh[idx] = (_Float16)((j < 16) ? cosf(wv) : sinf(wv));
    } else {
      int i2 = idx - nt;
      xh[i2] = (_Float16)x[i2];
    }
  }
  for (int i = blockIdx.x * 256 + threadIdx.x; i < n; i += gridDim.x * 256) deg[i] = 0;
}

// ---------- merged weight prep ----------
__global__ void k_prep(const float* __restrict__ inW, const float* __restrict__ qW,
                       const float* __restrict__ kW, const float* __restrict__ vW,
                       const float* __restrict__ oW, const float* __restrict__ qb,
                       const float* __restrict__ kb, const float* __restrict__ vb,
                       _Float16* __restrict__ inWt, _Float16* __restrict__ qkvWt,
                       float* __restrict__ qkvb, _Float16* __restrict__ oWt) {
  int idx = blockIdx.x * blockDim.x + threadIdx.x;
  const int S0 = 32 * HID;
  const int KQ = HID + TD;
  const int S1 = NL * QKVW * KQ;
  const int S2 = NL * QKVW;
  const int S3 = NL * HID * HID;
  if (idx < S0) {
    int nrow = idx / 32, k = idx - nrow * 32;
    inWt[idx] = (_Float16)inW[k * HID + nrow];
  } else if ((idx -= S0) < S1) {
    int l = idx / (QKVW * KQ);
    int rem = idx - l * (QKVW * KQ);
    int nrow = rem / KQ;
    int k = rem - nrow * KQ;
    float v;
    if (nrow < 256)      v = qW[(size_t)l * KQ * HID + (size_t)k * HID + nrow];
    else if (nrow < 512) v = kW[(size_t)l * KQ * HID + (size_t)k * HID + (nrow - 256)];
    else                 v = (k < HID) ? vW[(size_t)l * HID * HID + (size_t)k * HID + (nrow - 512)] : 0.f;
    qkvWt[idx] = (_Float16)v;
  } else if ((idx -= S1) < S2) {
    int l = idx / QKVW;
    int j = idx - l * QKVW;
    float v;
    if (j < 256)      v = qb[l * HID + j];
    else if (j < 512) v = kb[l * HID + (j - 256)];
    else              v = vb[l * HID + (j - 512)];
    qkvb[idx] = v;
  } else if ((idx -= S2) < S3) {
    int l = idx / (HID * HID);
    int rem = idx - l * (HID * HID);
    int nrow = rem / HID;
    int k = rem - nrow * HID;
    oWt[idx] = (_Float16)oW[(size_t)l * HID * HID + (size_t)k * HID + nrow];
  }
}

__global__ void k_count(const int* __restrict__ dst, int* deg, int e) {
  int i = blockIdx.x * blockDim.x + threadIdx.x;
  if (i < e) atomicAdd(&deg[dst[i]], 1);
}

// ---------- degree histogram / scan / permutation (load balancing) ----------
__global__ __launch_bounds__(256) void k_hist(const int* __restrict__ deg,
                                              int* __restrict__ hist, int n) {
  __shared__ int lh[256];
  lh[threadIdx.x] = 0;
  __syncthreads();
  int i = blockIdx.x * 256 + threadIdx.x;
  if (i < n) atomicAdd(&lh[min(deg[i], 255)], 1);
  __syncthreads();
  if (lh[threadIdx.x]) atomicAdd(&hist[threadIdx.x], lh[threadIdx.x]);
}

__global__ __launch_bounds__(256) void k_hscan(const int* __restrict__ hist,
                                               int* __restrict__ hoff) {
  int t = threadIdx.x;
  int v = hist[t];
  int lane = t & 63, w = t >> 6;
  int x = v;
#pragma unroll
  for (int off = 1; off < 64; off <<= 1) {
    int y = __shfl_up(x, off);
    if (lane >= off) x += y;
  }
  __shared__ int ws[4];
  if (lane == 63) ws[w] = x;
  __syncthreads();
  int wpre = 0;
  for (int i = 0; i < w; ++i) wpre += ws[i];
  hoff[t] = wpre + x - v;
}

__global__ __launch_bounds__(256) void k_perm(const int* __restrict__ deg,
                                              int* hoff, int* __restrict__ perm, int n) {
  int i = blockIdx.x * 256 + threadIdx.x;
  if (i >= n) return;
  int b = min(deg[i], 255);
  int p = atomicAdd(&hoff[b], 1);
  perm[p] = i;
}

// ---------- 3-kernel scan ----------
__global__ __launch_bounds__(256) void k_scan_part(const int* __restrict__ deg,
                                                   int* __restrict__ bsum, int n) {
  int t = threadIdx.x;
  int idx = blockIdx.x * 256 + t;
  int v = (idx < n) ? deg[idx] : 0;
  int lane = t & 63, w = t >> 6;
  int x = v;
#pragma unroll
  for (int off = 1; off < 64; off <<= 1) {
    int y = __shfl_up(x, off);
    if (lane >= off) x += y;
  }
  __shared__ int ws[4];
  if (lane == 63) ws[w] = x;
  __syncthreads();
  if (t == 0) bsum[blockIdx.x] = ws[0] + ws[1] + ws[2] + ws[3];
}

__global__ __launch_bounds__(64) void k_scan_mid(const int* __restrict__ bsum,
                                                 int* __restrict__ boff, int nb) {
  int lane = threadIdx.x;
  int carry = 0;
  for (int base = 0; base < nb; base += 64) {
    int i = base + lane;
    int v = (i < nb) ? bsum[i] : 0;
    int x = v;
#pragma unroll
    for (int off = 1; off < 64; off <<= 1) {
      int y = __shfl_up(x, off);
      if (lane >= off) x += y;
    }
    if (i < nb) boff[i] = carry + x - v;
    carry += __shfl(x, 63);
  }
}

__global__ __launch_bounds__(256) void k_scan_apply(const int* __restrict__ deg,
                                                    const int* __restrict__ boff,
                                                    int* __restrict__ row_ptr,
                                                    int* __restrict__ cursor, int n, int e) {
  int t = threadIdx.x;
  int idx = blockIdx.x * 256 + t;
  int v = (idx < n) ? deg[idx] : 0;
  int lane = t & 63, w = t >> 6;
  int x = v;
#pragma unroll
  for (int off = 1; off < 64; off <<= 1) {
    int y = __shfl_up(x, off);
    if (lane >= off) x += y;
  }
  __shared__ int ws[4];
  if (lane == 63) ws[w] = x;
  __syncthreads();
  int wpre = 0;
  for (int i = 0; i < w; ++i) wpre += ws[i];
  if (idx < n) {
    row_ptr[idx] = boff[blockIdx.x] + wpre + x - v;
    cursor[idx] = 0;
  }
  if (idx == 0) row_ptr[n] = e;
}

__global__ void k_scatter(const int* __restrict__ src, const int* __restrict__ dst,
                          const int* __restrict__ row_ptr, int* cursor,
                          int* __restrict__ colbuf, int e) {
  int i = blockIdx.x * blockDim.x + threadIdx.x;
  if (i >= e) return;
  int d = dst[i];
  int p = atomicAdd(&cursor[d], 1);
  colbuf[row_ptr[d] + p] = src[i];
}

// ---------- fp16 MFMA GEMM (128x64 tile, BK=32, 4 waves, double-buffered LDS) ----------
// mode 0: plain C write; mode 1: ELU C write; mode 2: QKV split write
__global__ __launch_bounds__(256) void k_gemm_f16(
    const _Float16* __restrict__ A1, int K1,
    const _Float16* __restrict__ A2, int K2,
    const _Float16* __restrict__ Bt,
    const float* __restrict__ bias,
    _Float16* __restrict__ C,
    _Float16* __restrict__ Qb,
    _Float16* __restrict__ KV,
    int M, int Ncols, int Ktot, int mode) {
  __shared__ half8 smem8[2 * 768];
  char* smem = (char*)smem8;
  const int tid = threadIdx.x;
  const int lane = tid & 63, wave = tid >> 6;
  const int wm = wave >> 1, wn = wave & 1;
  const int row0 = blockIdx.y * 128;
  const int col0 = blockIdx.x * 64;

  auto stage = [&](int buf, int k0) {
    char* sA = smem + buf * 12288;
    char* sB = sA + 8192;
#pragma unroll
    for (int i = 0; i < 2; ++i) {
      int kg = i * 2 + (wave >> 1);
      int row = (wave & 1) * 64 + lane;
      int grow = row0 + row; if (grow > M - 1) grow = M - 1;
      int k = k0 + kg * 8;
      const _Float16* src = (k < K1) ? (A1 + (size_t)grow * K1 + k)
                                     : (A2 + (size_t)grow * K2 + (k - K1));
      load16_to_lds(src, sA + (i * 256 + wave * 64) * 16);
    }
    {
      const _Float16* src = Bt + (size_t)(col0 + lane) * Ktot + k0 + wave * 8;
      load16_to_lds(src, sB + wave * 64 * 16);
    }
  };

  f32x4 acc[4][2];
#pragma unroll
  for (int mf = 0; mf < 4; ++mf)
#pragma unroll
    for (int nf = 0; nf < 2; ++nf) acc[mf][nf] = f32x4{0.f, 0.f, 0.f, 0.f};

  const int nsteps = Ktot >> 5;
  int cur = 0;
  stage(0, 0);
  __syncthreads();
  for (int st = 0; st < nsteps; ++st) {
    if (st + 1 < nsteps) stage(cur ^ 1, (st + 1) * 32);
    char* sA = smem + cur * 12288;
    char* sB = sA + 8192;
    half8 af[4], bf[2];
#pragma unroll
    for (int mf = 0; mf < 4; ++mf) {
      int slot = (lane >> 4) * 128 + wm * 64 + mf * 16 + (lane & 15);
      af[mf] = *(const half8*)(sA + slot * 16);
    }
#pragma unroll
    for (int nf = 0; nf < 2; ++nf) {
      int slot = (lane >> 4) * 64 + wn * 32 + nf * 16 + (lane & 15);
      bf[nf] = *(const half8*)(sB + slot * 16);
    }
#pragma unroll
    for (int mf = 0; mf < 4; ++mf)
#pragma unroll
      for (int nf = 0; nf < 2; ++nf)
        acc[mf][nf] = __builtin_amdgcn_mfma_f32_16x16x32_f16(af[mf], bf[nf], acc[mf][nf], 0, 0, 0);
    __syncthreads();
    cur ^= 1;
  }

  const int rbase = row0 + wm * 64 + (lane >> 4) * 4;
  const int cbase = col0 + wn * 32 + (lane & 15);
#pragma unroll
  for (int nf = 0; nf < 2; ++nf) {
    int col = cbase + nf * 16;
    float bv = bias[col];
    if (mode != 2) {
#pragma unroll
      for (int mf = 0; mf < 4; ++mf) {
#pragma unroll
        for (int r = 0; r < 4; ++r) {
          int row = rbase + mf * 16 + r;
          if (row < M) {
            float v = acc[mf][nf][r] + bv;
            if (mode == 1) v = (v > 0.f) ? v : expm1f(v);
            C[(size_t)row * Ncols + col] = (_Float16)v;
          }
        }
      }
    } else {
      bool isQ = col < 256;
      int cc = col - 256;
      int isV = cc >> 8;          // 0 = K, 1 = V (when !isQ)
      int c2 = cc & 255;
      int hh = c2 >> 5, dim = c2 & 31;
      size_t kvoff = ((size_t)hh * M) * 64 + isV * 32 + dim;
#pragma unroll
      for (int mf = 0; mf < 4; ++mf) {
#pragma unroll
        for (int r = 0; r < 4; ++r) {
          int row = rbase + mf * 16 + r;
          if (row < M) {
            float v = acc[mf][nf][r] + bv;
            if (isQ) Qb[(size_t)row * HID + col] = (_Float16)v;
            else     KV[kvoff + (size_t)row * 64] = (_Float16)v;
          }
        }
      }
    }
  }
}

// ---------- attention: head-split (L2-resident), fp16 K/V, 4 threads/node,
// nodes assigned via degree-sorted perm (wave gets 16 similar-degree nodes) ----------
__global__ __launch_bounds__(256) void k_attn(const _Float16* __restrict__ Qb,
                                              const _Float16* __restrict__ KV,
                                              const int* __restrict__ row_ptr,
                                              const int* __restrict__ colbuf,
                                              const int* __restrict__ perm,
                                              _Float16* __restrict__ out, int n) {
  int h = blockIdx.x & 7;
  int idx = (blockIdx.x >> 3) * 64 + (threadIdx.x >> 2);
  if (idx >= n) return;
  int node = perm[idx];
  int j = threadIdx.x & 3;   // dims j*8 .. j*8+7
  const float scale = 0.17677669529663687f;  // 1/sqrt(32)
  const _Float16* KVh = KV + ((size_t)h * n) * 64;

  half8 qh = *(const half8*)(Qb + (size_t)node * HID + h * 32 + j * 8);
  half8 qs;
#pragma unroll
  for (int q = 0; q < 8; ++q) qs[q] = (_Float16)((float)qh[q] * scale);

  int beg = row_ptr[node], end = row_ptr[node + 1];
  float m = -INFINITY, s = 0.f;
  float a[8] = {0.f, 0.f, 0.f, 0.f, 0.f, 0.f, 0.f, 0.f};

  for (int i = beg; i < end; i += 4) {
    half8 kk[4], vv[4];
#pragma unroll
    for (int t = 0; t < 4; ++t) {
      int ii = i + t; if (ii > end - 1) ii = end - 1;
      int sn = colbuf[ii];
      const _Float16* b = KVh + ((size_t)sn) * 64 + j * 8;
      kk[t] = *(const half8*)(b);
      vv[t] = *(const half8*)(b + 32);
    }
    float p[4];
#pragma unroll
    for (int t = 0; t < 4; ++t) p[t] = dot8h(qs, kk[t], 0.f);
#pragma unroll
    for (int t = 0; t < 4; ++t) {
      p[t] += __shfl_xor(p[t], 1);
      p[t] += __shfl_xor(p[t], 2);
      if (i + t >= end) p[t] = -INFINITY;  // tail mask (t=0 always real)
    }
#pragma unroll
    for (int t = 0; t < 4; ++t) {
      float sc_ = p[t];
      if (sc_ <= m) {
        float e2 = __expf(sc_ - m);
        s += e2;
#pragma unroll
        for (int q = 0; q < 8; ++q) a[q] = fmaf(e2, (float)vv[t][q], a[q]);
      } else {
        float f = __expf(m - sc_);  // m=-inf on first real edge -> f=0
        s = s * f + 1.f;
#pragma unroll
        for (int q = 0; q < 8; ++q) a[q] = fmaf(a[q], f, (float)vv[t][q]);
        m = sc_;
      }
    }
  }

  float inv = (s > 0.f) ? (1.f / s) : 0.f;
  half8 o;
#pragma unroll
  for (int q = 0; q < 8; ++q) o[q] = (_Float16)(a[q] * inv);
  *(half8*)(out + (size_t)node * HID + h * 32 + j * 8) = o;
}

// ---------- pooling + classifier ----------
__global__ __launch_bounds__(256) void k_pool_partial(const _Float16* __restrict__ h,
                                                      float* __restrict__ partial, int n) {
  int b = blockIdx.x, t = threadIdx.x;
  float s = 0.f;
  for (int r = b; r < n; r += 256) s += (float)h[(size_t)r * HID + t];
  partial[b * HID + t] = s;
}

__global__ __launch_bounds__(256) void k_final(const float* __restrict__ partial,
                                               const float* __restrict__ c1W,
                                               const float* __restrict__ c1b,
                                               const float* __restrict__ c2W,
                                               const float* __restrict__ c2b,
                                               float* __restrict__ out, int n) {
  __shared__ float gl[HID];
  __shared__ float r1[C1DIM];
  int t = threadIdx.x;
  float s = 0.f;
  for (int b = 0; b < 256; b++) s += partial[b * HID + t];
  gl[t] = s / (float)n;
  __syncthreads();
  if (t < C1DIM) {
    float a = c1b[t];
    for (int k = 0; k < HID; k++) a += gl[k] * c1W[k * C1DIM + t];
    r1[t] = fmaxf(a, 0.f);
  }
  __syncthreads();
  if (t < OUTDIM) {
    float a = c2b[t];
    for (int k = 0; k < C1DIM; k++) a += r1[k] * c2W[k * OUTDIM + t];
    out[t] = a;
  }
}

// ---------- host launcher ----------
extern "C" void kernel_launch(void* const* d_in, const int* in_sizes, int n_in,
                              void* d_out, int out_size, void* d_ws, size_t ws_size,
                              hipStream_t stream) {
  const float* x    = (const float*)d_in[0];
  const float* ts   = (const float*)d_in[1];
  const int*   ei   = (const int*)d_in[2];
  const float* freq = (const float*)d_in[4];
  const float* inW  = (const float*)d_in[5];
  const float* inb  = (const float*)d_in[6];
  const float* qW   = (const float*)d_in[7];
  const float* qb   = (const float*)d_in[8];
  const float* kW   = (const float*)d_in[9];
  const float* kb   = (const float*)d_in[10];
  const float* vW   = (const float*)d_in[11];
  const float* vb   = (const float*)d_in[12];
  const float* oW   = (const float*)d_in[13];
  const float* ob   = (const float*)d_in[14];
  const float* c1W  = (const float*)d_in[15];
  const float* c1b  = (const float*)d_in[16];
  const float* c2W  = (const float*)d_in[17];
  const float* c2b  = (const float*)d_in[18];

  int n = in_sizes[1];
  int e = in_sizes[2] / 2;
  const int* src = ei;
  const int* dst = ei + e;
  int nb = (n + 255) / 256;

  char* w = (char*)d_ws;
  size_t off = 0;
  auto alloc = [&](size_t bytes) -> char* {
    char* p = w + off;
    off = (off + bytes + 255) & ~(size_t)255;
    return p;
  };
  _Float16* tfh     = (_Float16*)alloc((size_t)n * TD * 2);
  _Float16* xh      = (_Float16*)alloc((size_t)n * 32 * 2);
  _Float16* h       = (_Float16*)alloc((size_t)n * HID * 2);
  _Float16* Qbuf    = (_Float16*)alloc((size_t)n * HID * 2);
  _Float16* KV      = (_Float16*)alloc((size_t)n * 512 * 2);  // 8 heads x 64 halves
  _Float16* ao      = (_Float16*)alloc((size_t)n * HID * 2);
  _Float16* inWt    = (_Float16*)alloc((size_t)32 * HID * 2);
  _Float16* qkvWt   = (_Float16*)alloc((size_t)NL * QKVW * (HID + TD) * 2);
  float*    qkvb    = (float*)alloc((size_t)NL * QKVW * 4);
  _Float16* oWt     = (_Float16*)alloc((size_t)NL * HID * HID * 2);
  int*      deg     = (int*)alloc((size_t)n * 4);
  int*      cursor  = (int*)alloc((size_t)n * 4);
  int*      row_ptr = (int*)alloc((size_t)(n + 1) * 4);
  int*      colbuf  = (int*)alloc((size_t)e * 4);
  int*      bsum    = (int*)alloc((size_t)nb * 4);
  int*      boff    = (int*)alloc((size_t)nb * 4);
  int*      hist    = (int*)alloc(256 * 4);
  int*      hoff    = (int*)alloc(256 * 4);
  int*      perm    = (int*)alloc((size_t)n * 4);
  float*    partial = (float*)alloc((size_t)256 * HID * 4);

  int b256 = 256;
  hipMemsetAsync(hist, 0, 256 * 4, stream);
  hipLaunchKernelGGL(k_enc, dim3(512), dim3(b256), 0, stream,
                     ts, freq, x, tfh, xh, deg, n);
  {
    int total = 32 * HID + NL * QKVW * (HID + TD) + NL * QKVW + NL * HID * HID;
    hipLaunchKernelGGL(k_prep, dim3((total + 255) / 256), dim3(b256), 0, stream,
                       inW, qW, kW, vW, oW, qb, kb, vb, inWt, qkvWt, qkvb, oWt);
  }
  hipLaunchKernelGGL(k_count, dim3((e + 255) / 256), dim3(b256), 0, stream, dst, deg, e);
  hipLaunchKernelGGL(k_hist, dim3(nb), dim3(b256), 0, stream, deg, hist, n);
  hipLaunchKernelGGL(k_hscan, dim3(1), dim3(b256), 0, stream, hist, hoff);
  hipLaunchKernelGGL(k_perm, dim3(nb), dim3(b256), 0, stream, deg, hoff, perm, n);
  hipLaunchKernelGGL(k_scan_part, dim3(nb), dim3(b256), 0, stream, deg, bsum, n);
  hipLaunchKernelGGL(k_scan_mid, dim3(1), dim3(64), 0, stream, bsum, boff, nb);
  hipLaunchKernelGGL(k_scan_apply, dim3(nb), dim3(b256), 0, stream, deg, boff, row_ptr, cursor, n, e);
  hipLaunchKernelGGL(k_scatter, dim3((e + 255) / 256), dim3(b256), 0, stream, src, dst, row_ptr, cursor, colbuf, e);

  dim3 ggrid_h(HID / 64, (n + 127) / 128);
  dim3 ggrid_qkv(QKVW / 64, (n + 127) / 128);
  hipLaunchKernelGGL(k_gemm_f16, ggrid_h, dim3(b256), 0, stream,
                     xh, 32, xh, 32, inWt, inb, h, (_Float16*)nullptr, (_Float16*)nullptr,
                     n, HID, 32, 0);

  int nchunks = (n + 63) / 64;
  for (int l = 0; l < NL; ++l) {
    const _Float16* qkvWtl = qkvWt + (size_t)l * QKVW * (HID + TD);
    const float*    qkvbl  = qkvb + (size_t)l * QKVW;
    const _Float16* oWtl   = oWt + (size_t)l * HID * HID;
    hipLaunchKernelGGL(k_gemm_f16, ggrid_qkv, dim3(b256), 0, stream,
                       h, HID, tfh, TD, qkvWtl, qkvbl, (_Float16*)nullptr, Qbuf, KV,
                       n, QKVW, HID + TD, 2);
    hipLaunchKernelGGL(k_attn, dim3(nchunks * 8), dim3(b256), 0, stream,
                       Qbuf, KV, row_ptr, colbuf, perm, ao, n);
    hipLaunchKernelGGL(k_gemm_f16, ggrid_h, dim3(b256), 0, stream,
                       ao, HID, ao, HID, oWtl, ob + l * HID, h, (_Float16*)nullptr, (_Float16*)nullptr,
                       n, HID, HID, 1);
  }

  hipLaunchKernelGGL(k_pool_partial, dim3(256), dim3(b256), 0, stream, h, partial, n);
  hipLaunchKernelGGL(k_final, dim3(1), dim3(b256), 0, stream, partial, c1W, c1b, c2W, c2b, (float*)d_out, n);
}

// Round 13
// 493.541 us; speedup vs baseline: 1.0965x; 1.0965x over previous
//
#include <hip/hip_runtime.h>
#include <math.h>

#define HID 256
#define TD 32
#define NL 3
#define C1DIM 128
#define OUTDIM 2
#define QKVW 768

using half8  = __attribute__((ext_vector_type(8))) _Float16;
using half2v = __attribute__((ext_vector_type(2))) _Float16;
using f32x4  = __attribute__((ext_vector_type(4))) float;

typedef __attribute__((address_space(1))) void gbl_void_t;
typedef __attribute__((address_space(3))) void lds_void_t;

__device__ __forceinline__ void load16_to_lds(const void* g, void* l) {
  __builtin_amdgcn_global_load_lds((const gbl_void_t*)g, (lds_void_t*)l, 16, 0, 0);
}

__device__ __forceinline__ float dot8h(half8 a, half8 b, float acc) {
#if __has_builtin(__builtin_amdgcn_fdot2)
  union { half8 v; half2v h2[4]; } ua, ub;
  ua.v = a; ub.v = b;
#pragma unroll
  for (int j = 0; j < 4; ++j) acc = __builtin_amdgcn_fdot2(ua.h2[j], ub.h2[j], acc, false);
  return acc;
#else
#pragma unroll
  for (int j = 0; j < 8; ++j) acc += (float)a[j] * (float)b[j];
  return acc;
#endif
}

// ---------- fused setup: [0,512) enc | qkv transpose | o transpose | in transpose | bias ----------
// deg is zeroed by hipMemsetAsync before this kernel.
#define NB_ENC 512
#define NB_QKV (NL * 9 * 12)   // k-tiles 288/32 x n-tiles 768/64
#define NB_O   (NL * 8 * 4)    // 256/32 x 256/64
#define NB_IN  4               // 1 k-tile x 256/64
#define NB_B   9               // NL*768 / 256

__global__ __launch_bounds__(256) void k_setup(
    const float* __restrict__ ts, const float* __restrict__ freq,
    const float* __restrict__ x,
    const float* __restrict__ inW, const float* __restrict__ qW,
    const float* __restrict__ kW, const float* __restrict__ vW,
    const float* __restrict__ oW, const float* __restrict__ qb,
    const float* __restrict__ kb, const float* __restrict__ vb,
    _Float16* __restrict__ tfh, _Float16* __restrict__ xh,
    _Float16* __restrict__ inWt, _Float16* __restrict__ qkvWt,
    float* __restrict__ qkvb, _Float16* __restrict__ oWt, int n) {
  __shared__ _Float16 lds[32][65];
  int bid = blockIdx.x;
  int t = threadIdx.x;
  const int KQ = HID + TD;  // 288

  if (bid < NB_ENC) {
    // ---- time encoding + x conversion (per-block redundant min/max) ----
    float lmin = INFINITY, lmax = -INFINITY;
    for (int i = t; i < n; i += 256) {
      float v = ts[i];
      lmin = fminf(lmin, v); lmax = fmaxf(lmax, v);
    }
#pragma unroll
    for (int off = 32; off >= 1; off >>= 1) {
      lmin = fminf(lmin, __shfl_xor(lmin, off));
      lmax = fmaxf(lmax, __shfl_xor(lmax, off));
    }
    __shared__ float wmin[4], wmax[4];
    int lane = t & 63, w = t >> 6;
    if (lane == 0) { wmin[w] = lmin; wmax[w] = lmax; }
    __syncthreads();
    float tmin = fminf(fminf(wmin[0], wmin[1]), fminf(wmin[2], wmin[3]));
    float tmax = fmaxf(fmaxf(wmax[0], wmax[1]), fmaxf(wmax[2], wmax[3]));
    float inv = 1.f / (tmax - tmin + 1e-8f);
    int nt = n * TD;
    int total = n * 64;
    for (int idx = bid * 256 + t; idx < total; idx += NB_ENC * 256) {
      if (idx < nt) {
        int node = idx >> 5, j = idx & 31;
        float tv = (ts[node] - tmin) * inv;
        float wv = tv * freq[j & 15];
        tfh[idx] = (_Float16)((j < 16) ? cosf(wv) : sinf(wv));
      } else {
        int i2 = idx - nt;
        xh[i2] = (_Float16)x[i2];
      }
    }
    return;
  }
  bid -= NB_ENC;

  if (bid < NB_QKV) {
    // ---- qkvWt transpose: Wt[l][nrow][k] from qW/kW/vW [l][k][nrow] ----
    int l = bid / 108;
    int rem = bid - l * 108;
    int kt = rem / 12, ntile = rem - kt * 12;
    int k0 = kt * 32, n0 = ntile * 64;
#pragma unroll
    for (int it = 0; it < 8; ++it) {
      int i = it * 256 + t;
      int kk = i >> 6, nn = i & 63;
      int k = k0 + kk, nrow = n0 + nn;
      float v;
      if (nrow < 256)      v = qW[(size_t)l * KQ * HID + (size_t)k * HID + nrow];
      else if (nrow < 512) v = kW[(size_t)l * KQ * HID + (size_t)k * HID + (nrow - 256)];
      else                 v = (k < HID) ? vW[(size_t)l * HID * HID + (size_t)k * HID + (nrow - 512)] : 0.f;
      lds[kk][nn] = (_Float16)v;
    }
    __syncthreads();
    {
      int nn = t >> 2, kq = (t & 3) * 8;
      _Float16* dst = qkvWt + (size_t)l * QKVW * KQ + (size_t)(n0 + nn) * KQ + k0 + kq;
      half8 v;
#pragma unroll
      for (int j = 0; j < 8; ++j) v[j] = lds[kq + j][nn];
      *(half8*)dst = v;
    }
    return;
  }
  bid -= NB_QKV;

  if (bid < NB_O) {
    // ---- oWt transpose: Wt[l][nrow][k] from oW [l][k][nrow], 256x256 ----
    int l = bid / 32;
    int rem = bid - l * 32;
    int kt = rem / 4, ntile = rem - kt * 4;
    int k0 = kt * 32, n0 = ntile * 64;
#pragma unroll
    for (int it = 0; it < 8; ++it) {
      int i = it * 256 + t;
      int kk = i >> 6, nn = i & 63;
      lds[kk][nn] = (_Float16)oW[(size_t)l * HID * HID + (size_t)(k0 + kk) * HID + n0 + nn];
    }
    __syncthreads();
    {
      int nn = t >> 2, kq = (t & 3) * 8;
      _Float16* dst = oWt + (size_t)l * HID * HID + (size_t)(n0 + nn) * HID + k0 + kq;
      half8 v;
#pragma unroll
      for (int j = 0; j < 8; ++j) v[j] = lds[kq + j][nn];
      *(half8*)dst = v;
    }
    return;
  }
  bid -= NB_O;

  if (bid < NB_IN) {
    // ---- inWt transpose: Wt[nrow][k] from inW [32][256] ----
    int n0 = bid * 64;
#pragma unroll
    for (int it = 0; it < 8; ++it) {
      int i = it * 256 + t;
      int kk = i >> 6, nn = i & 63;
      lds[kk][nn] = (_Float16)inW[(size_t)kk * HID + n0 + nn];
    }
    __syncthreads();
    {
      int nn = t >> 2, kq = (t & 3) * 8;
      _Float16* dst = inWt + (size_t)(n0 + nn) * 32 + kq;
      half8 v;
#pragma unroll
      for (int j = 0; j < 8; ++j) v[j] = lds[kq + j][nn];
      *(half8*)dst = v;
    }
    return;
  }
  bid -= NB_IN;

  {
    // ---- fused qkv bias ----
    int idx = bid * 256 + t;
    if (idx < NL * QKVW) {
      int l = idx / QKVW;
      int j = idx - l * QKVW;
      float v;
      if (j < 256)      v = qb[l * HID + j];
      else if (j < 512) v = kb[l * HID + (j - 256)];
      else              v = vb[l * HID + (j - 512)];
      qkvb[idx] = v;
    }
  }
}

__global__ void k_count(const int* __restrict__ dst, int* deg, int e) {
  int i = blockIdx.x * blockDim.x + threadIdx.x;
  if (i < e) atomicAdd(&deg[dst[i]], 1);
}

// ---------- 3-kernel scan ----------
__global__ __launch_bounds__(256) void k_scan_part(const int* __restrict__ deg,
                                                   int* __restrict__ bsum, int n) {
  int t = threadIdx.x;
  int idx = blockIdx.x * 256 + t;
  int v = (idx < n) ? deg[idx] : 0;
  int lane = t & 63, w = t >> 6;
  int x = v;
#pragma unroll
  for (int off = 1; off < 64; off <<= 1) {
    int y = __shfl_up(x, off);
    if (lane >= off) x += y;
  }
  __shared__ int ws[4];
  if (lane == 63) ws[w] = x;
  __syncthreads();
  if (t == 0) bsum[blockIdx.x] = ws[0] + ws[1] + ws[2] + ws[3];
}

__global__ __launch_bounds__(64) void k_scan_mid(const int* __restrict__ bsum,
                                                 int* __restrict__ boff, int nb) {
  int lane = threadIdx.x;
  int carry = 0;
  for (int base = 0; base < nb; base += 64) {
    int i = base + lane;
    int v = (i < nb) ? bsum[i] : 0;
    int x = v;
#pragma unroll
    for (int off = 1; off < 64; off <<= 1) {
      int y = __shfl_up(x, off);
      if (lane >= off) x += y;
    }
    if (i < nb) boff[i] = carry + x - v;
    carry += __shfl(x, 63);
  }
}

__global__ __launch_bounds__(256) void k_scan_apply(const int* __restrict__ deg,
                                                    const int* __restrict__ boff,
                                                    int* __restrict__ row_ptr,
                                                    int* __restrict__ cursor, int n, int e) {
  int t = threadIdx.x;
  int idx = blockIdx.x * 256 + t;
  int v = (idx < n) ? deg[idx] : 0;
  int lane = t & 63, w = t >> 6;
  int x = v;
#pragma unroll
  for (int off = 1; off < 64; off <<= 1) {
    int y = __shfl_up(x, off);
    if (lane >= off) x += y;
  }
  __shared__ int ws[4];
  if (lane == 63) ws[w] = x;
  __syncthreads();
  int wpre = 0;
  for (int i = 0; i < w; ++i) wpre += ws[i];
  if (idx < n) {
    row_ptr[idx] = boff[blockIdx.x] + wpre + x - v;
    cursor[idx] = 0;
  }
  if (idx == 0) row_ptr[n] = e;
}

__global__ void k_scatter(const int* __restrict__ src, const int* __restrict__ dst,
                          const int* __restrict__ row_ptr, int* cursor,
                          int* __restrict__ colbuf, int e) {
  int i = blockIdx.x * blockDim.x + threadIdx.x;
  if (i >= e) return;
  int d = dst[i];
  int p = atomicAdd(&cursor[d], 1);
  colbuf[row_ptr[d] + p] = src[i];
}

// ---------- fp16 MFMA GEMM (128x64 tile, BK=32, 4 waves, double-buffered LDS) ----------
// mode 0: plain; mode 1: ELU
__global__ __launch_bounds__(256) void k_gemm_f16(
    const _Float16* __restrict__ A1, int K1,
    const _Float16* __restrict__ A2, int K2,
    const _Float16* __restrict__ Bt,
    const float* __restrict__ bias,
    _Float16* __restrict__ C,
    int M, int Ncols, int Ktot, int mode) {
  __shared__ half8 smem8[2 * 768];
  char* smem = (char*)smem8;
  const int tid = threadIdx.x;
  const int lane = tid & 63, wave = tid >> 6;
  const int wm = wave >> 1, wn = wave & 1;
  const int row0 = blockIdx.y * 128;
  const int col0 = blockIdx.x * 64;

  auto stage = [&](int buf, int k0) {
    char* sA = smem + buf * 12288;
    char* sB = sA + 8192;
#pragma unroll
    for (int i = 0; i < 2; ++i) {
      int kg = i * 2 + (wave >> 1);
      int row = (wave & 1) * 64 + lane;
      int grow = row0 + row; if (grow > M - 1) grow = M - 1;
      int k = k0 + kg * 8;
      const _Float16* src = (k < K1) ? (A1 + (size_t)grow * K1 + k)
                                     : (A2 + (size_t)grow * K2 + (k - K1));
      load16_to_lds(src, sA + (i * 256 + wave * 64) * 16);
    }
    {
      const _Float16* src = Bt + (size_t)(col0 + lane) * Ktot + k0 + wave * 8;
      load16_to_lds(src, sB + wave * 64 * 16);
    }
  };

  f32x4 acc[4][2];
#pragma unroll
  for (int mf = 0; mf < 4; ++mf)
#pragma unroll
    for (int nf = 0; nf < 2; ++nf) acc[mf][nf] = f32x4{0.f, 0.f, 0.f, 0.f};

  const int nsteps = Ktot >> 5;
  int cur = 0;
  stage(0, 0);
  __syncthreads();
  for (int st = 0; st < nsteps; ++st) {
    if (st + 1 < nsteps) stage(cur ^ 1, (st + 1) * 32);
    char* sA = smem + cur * 12288;
    char* sB = sA + 8192;
    half8 af[4], bf[2];
#pragma unroll
    for (int mf = 0; mf < 4; ++mf) {
      int slot = (lane >> 4) * 128 + wm * 64 + mf * 16 + (lane & 15);
      af[mf] = *(const half8*)(sA + slot * 16);
    }
#pragma unroll
    for (int nf = 0; nf < 2; ++nf) {
      int slot = (lane >> 4) * 64 + wn * 32 + nf * 16 + (lane & 15);
      bf[nf] = *(const half8*)(sB + slot * 16);
    }
#pragma unroll
    for (int mf = 0; mf < 4; ++mf)
#pragma unroll
      for (int nf = 0; nf < 2; ++nf)
        acc[mf][nf] = __builtin_amdgcn_mfma_f32_16x16x32_f16(af[mf], bf[nf], acc[mf][nf], 0, 0, 0);
    __syncthreads();
    cur ^= 1;
  }

  const int rbase = row0 + wm * 64 + (lane >> 4) * 4;
  const int cbase = col0 + wn * 32 + (lane & 15);
#pragma unroll
  for (int nf = 0; nf < 2; ++nf) {
    int col = cbase + nf * 16;
    float bv = bias[col];
#pragma unroll
    for (int mf = 0; mf < 4; ++mf) {
#pragma unroll
      for (int r = 0; r < 4; ++r) {
        int row = rbase + mf * 16 + r;
        if (row < M) {
          float v = acc[mf][nf][r] + bv;
          if (mode == 1) v = (v > 0.f) ? v : expm1f(v);
          C[(size_t)row * Ncols + col] = (_Float16)v;
        }
      }
    }
  }
}

// ---------- QKV GEMM: 128x128 tile, BK=32, 4 waves (each 64x64), split epilogue ----------
__global__ __launch_bounds__(256) void k_gemm_qkv(
    const _Float16* __restrict__ A1, int K1,
    const _Float16* __restrict__ A2, int K2,
    const _Float16* __restrict__ Bt,
    const float* __restrict__ bias,
    _Float16* __restrict__ Qb,
    _Float16* __restrict__ KV,
    int M, int Ktot) {
  __shared__ half8 smem8[2048];  // 2 bufs x (8KB A + 8KB B) = 32KB
  char* smem = (char*)smem8;
  const int tid = threadIdx.x;
  const int lane = tid & 63, wave = tid >> 6;
  const int wm = wave >> 1, wn = wave & 1;
  const int row0 = blockIdx.y * 128;
  const int col0 = blockIdx.x * 128;

  auto stage = [&](int buf, int k0) {
    char* sA = smem + buf * 16384;
    char* sB = sA + 8192;
    int k = k0 + wave * 8;
#pragma unroll
    for (int j = 0; j < 2; ++j) {
      int row = j * 64 + lane;
      int grow = row0 + row; if (grow > M - 1) grow = M - 1;
      const _Float16* srcA = (k < K1) ? (A1 + (size_t)grow * K1 + k)
                                      : (A2 + (size_t)grow * K2 + (k - K1));
      load16_to_lds(srcA, sA + (wave * 128 + j * 64) * 16);
    }
#pragma unroll
    for (int j = 0; j < 2; ++j) {
      int col = j * 64 + lane;
      const _Float16* srcB = Bt + (size_t)(col0 + col) * Ktot + k;
      load16_to_lds(srcB, sB + (wave * 128 + j * 64) * 16);
    }
  };

  f32x4 acc[4][4];
#pragma unroll
  for (int mf = 0; mf < 4; ++mf)
#pragma unroll
    for (int nf = 0; nf < 4; ++nf) acc[mf][nf] = f32x4{0.f, 0.f, 0.f, 0.f};

  const int nsteps = Ktot >> 5;
  int cur = 0;
  stage(0, 0);
  __syncthreads();
  for (int st = 0; st < nsteps; ++st) {
    if (st + 1 < nsteps) stage(cur ^ 1, (st + 1) * 32);
    char* sA = smem + cur * 16384;
    char* sB = sA + 8192;
    half8 af[4], bf[4];
#pragma unroll
    for (int mf = 0; mf < 4; ++mf) {
      int slot = (lane >> 4) * 128 + wm * 64 + mf * 16 + (lane & 15);
      af[mf] = *(const half8*)(sA + slot * 16);
    }
#pragma unroll
    for (int nf = 0; nf < 4; ++nf) {
      int slot = (lane >> 4) * 128 + wn * 64 + nf * 16 + (lane & 15);
      bf[nf] = *(const half8*)(sB + slot * 16);
    }
#pragma unroll
    for (int mf = 0; mf < 4; ++mf)
#pragma unroll
      for (int nf = 0; nf < 4; ++nf)
        acc[mf][nf] = __builtin_amdgcn_mfma_f32_16x16x32_f16(af[mf], bf[nf], acc[mf][nf], 0, 0, 0);
    __syncthreads();
    cur ^= 1;
  }

  const int rbase = row0 + wm * 64 + (lane >> 4) * 4;
  const int cbase = col0 + wn * 64 + (lane & 15);
#pragma unroll
  for (int nf = 0; nf < 4; ++nf) {
    int col = cbase + nf * 16;
    float bv = bias[col];
    bool isQ = col < 256;
    int cc = col - 256;
    int isV = cc >> 8;
    int c2 = cc & 255;
    int hh = c2 >> 5, dim = c2 & 31;
    size_t kvoff = ((size_t)hh * M) * 64 + isV * 32 + dim;
#pragma unroll
    for (int mf = 0; mf < 4; ++mf) {
#pragma unroll
      for (int r = 0; r < 4; ++r) {
        int row = rbase + mf * 16 + r;
        if (row < M) {
          float v = acc[mf][nf][r] + bv;
          if (isQ) Qb[(size_t)row * HID + col] = (_Float16)v;
          else     KV[kvoff + (size_t)row * 64] = (_Float16)v;
        }
      }
    }
  }
}

// ---------- attention: head-split (L2-resident), fp16 K/V, 4 threads/node ----------
// head = blockIdx.x & 7 (XCD round-robin); 64 nodes/block, 4 threads/node (8 dims each)
__global__ __launch_bounds__(256) void k_attn(const _Float16* __restrict__ Qb,
                                              const _Float16* __restrict__ KV,
                                              const int* __restrict__ row_ptr,
                                              const int* __restrict__ colbuf,
                                              _Float16* __restrict__ out, int n) {
  int h = blockIdx.x & 7;
  int node = (blockIdx.x >> 3) * 64 + (threadIdx.x >> 2);
  if (node >= n) return;
  int j = threadIdx.x & 3;   // dims j*8 .. j*8+7
  const float scale = 0.17677669529663687f;  // 1/sqrt(32)
  const _Float16* KVh = KV + ((size_t)h * n) * 64;

  half8 qh = *(const half8*)(Qb + (size_t)node * HID + h * 32 + j * 8);
  half8 qs;
#pragma unroll
  for (int q = 0; q < 8; ++q) qs[q] = (_Float16)((float)qh[q] * scale);

  int beg = row_ptr[node], end = row_ptr[node + 1];
  float m = -INFINITY, s = 0.f;
  float a[8] = {0.f, 0.f, 0.f, 0.f, 0.f, 0.f, 0.f, 0.f};

  for (int i = beg; i < end; i += 4) {
    half8 kk[4], vv[4];
#pragma unroll
    for (int t = 0; t < 4; ++t) {
      int ii = i + t; if (ii > end - 1) ii = end - 1;
      int sn = colbuf[ii];
      const _Float16* b = KVh + ((size_t)sn) * 64 + j * 8;
      kk[t] = *(const half8*)(b);
      vv[t] = *(const half8*)(b + 32);
    }
    float p[4];
#pragma unroll
    for (int t = 0; t < 4; ++t) p[t] = dot8h(qs, kk[t], 0.f);
#pragma unroll
    for (int t = 0; t < 4; ++t) {
      p[t] += __shfl_xor(p[t], 1);
      p[t] += __shfl_xor(p[t], 2);
      if (i + t >= end) p[t] = -INFINITY;  // tail mask (t=0 always real)
    }
#pragma unroll
    for (int t = 0; t < 4; ++t) {
      float sc_ = p[t];
      if (sc_ <= m) {
        float e2 = __expf(sc_ - m);
        s += e2;
#pragma unroll
        for (int q = 0; q < 8; ++q) a[q] = fmaf(e2, (float)vv[t][q], a[q]);
      } else {
        float f = __expf(m - sc_);  // m=-inf on first real edge -> f=0
        s = s * f + 1.f;
#pragma unroll
        for (int q = 0; q < 8; ++q) a[q] = fmaf(a[q], f, (float)vv[t][q]);
        m = sc_;
      }
    }
  }

  float inv = (s > 0.f) ? (1.f / s) : 0.f;
  half8 o;
#pragma unroll
  for (int q = 0; q < 8; ++q) o[q] = (_Float16)(a[q] * inv);
  *(half8*)(out + (size_t)node * HID + h * 32 + j * 8) = o;
}

// ---------- pooling + classifier ----------
__global__ __launch_bounds__(256) void k_pool_partial(const _Float16* __restrict__ h,
                                                      float* __restrict__ partial, int n) {
  int b = blockIdx.x, t = threadIdx.x;
  float s = 0.f;
  for (int r = b; r < n; r += 256) s += (float)h[(size_t)r * HID + t];
  partial[b * HID + t] = s;
}

__global__ __launch_bounds__(256) void k_final(const float* __restrict__ partial,
                                               const float* __restrict__ c1W,
                                               const float* __restrict__ c1b,
                                               const float* __restrict__ c2W,
                                               const float* __restrict__ c2b,
                                               float* __restrict__ out, int n) {
  __shared__ float gl[HID];
  __shared__ float r1[C1DIM];
  int t = threadIdx.x;
  float s = 0.f;
  for (int b = 0; b < 256; b++) s += partial[b * HID + t];
  gl[t] = s / (float)n;
  __syncthreads();
  if (t < C1DIM) {
    float a = c1b[t];
    for (int k = 0; k < HID; k++) a += gl[k] * c1W[k * C1DIM + t];
    r1[t] = fmaxf(a, 0.f);
  }
  __syncthreads();
  if (t < OUTDIM) {
    float a = c2b[t];
    for (int k = 0; k < C1DIM; k++) a += r1[k] * c2W[k * OUTDIM + t];
    out[t] = a;
  }
}

// ---------- host launcher ----------
extern "C" void kernel_launch(void* const* d_in, const int* in_sizes, int n_in,
                              void* d_out, int out_size, void* d_ws, size_t ws_size,
                              hipStream_t stream) {
  const float* x    = (const float*)d_in[0];
  const float* ts   = (const float*)d_in[1];
  const int*   ei   = (const int*)d_in[2];
  const float* freq = (const float*)d_in[4];
  const float* inW  = (const float*)d_in[5];
  const float* inb  = (const float*)d_in[6];
  const float* qW   = (const float*)d_in[7];
  const float* qb   = (const float*)d_in[8];
  const float* kW   = (const float*)d_in[9];
  const float* kb   = (const float*)d_in[10];
  const float* vW   = (const float*)d_in[11];
  const float* vb   = (const float*)d_in[12];
  const float* oW   = (const float*)d_in[13];
  const float* ob   = (const float*)d_in[14];
  const float* c1W  = (const float*)d_in[15];
  const float* c1b  = (const float*)d_in[16];
  const float* c2W  = (const float*)d_in[17];
  const float* c2b  = (const float*)d_in[18];

  int n = in_sizes[1];
  int e = in_sizes[2] / 2;
  const int* src = ei;
  const int* dst = ei + e;
  int nb = (n + 255) / 256;

  char* w = (char*)d_ws;
  size_t off = 0;
  auto alloc = [&](size_t bytes) -> char* {
    char* p = w + off;
    off = (off + bytes + 255) & ~(size_t)255;
    return p;
  };
  _Float16* tfh     = (_Float16*)alloc((size_t)n * TD * 2);
  _Float16* xh      = (_Float16*)alloc((size_t)n * 32 * 2);
  _Float16* h       = (_Float16*)alloc((size_t)n * HID * 2);
  _Float16* Qbuf    = (_Float16*)alloc((size_t)n * HID * 2);
  _Float16* KV      = (_Float16*)alloc((size_t)n * 512 * 2);  // 8 heads x 64 halves
  _Float16* ao      = (_Float16*)alloc((size_t)n * HID * 2);
  _Float16* inWt    = (_Float16*)alloc((size_t)32 * HID * 2);
  _Float16* qkvWt   = (_Float16*)alloc((size_t)NL * QKVW * (HID + TD) * 2);
  float*    qkvb    = (float*)alloc((size_t)NL * QKVW * 4);
  _Float16* oWt     = (_Float16*)alloc((size_t)NL * HID * HID * 2);
  int*      deg     = (int*)alloc((size_t)n * 4);
  int*      cursor  = (int*)alloc((size_t)n * 4);
  int*      row_ptr = (int*)alloc((size_t)(n + 1) * 4);
  int*      colbuf  = (int*)alloc((size_t)e * 4);
  int*      bsum    = (int*)alloc((size_t)nb * 4);
  int*      boff    = (int*)alloc((size_t)nb * 4);
  float*    partial = (float*)alloc((size_t)256 * HID * 4);

  int b256 = 256;
  hipMemsetAsync(deg, 0, (size_t)n * 4, stream);
  {
    int nblk = NB_ENC + NB_QKV + NB_O + NB_IN + NB_B;
    hipLaunchKernelGGL(k_setup, dim3(nblk), dim3(b256), 0, stream,
                       ts, freq, x, inW, qW, kW, vW, oW, qb, kb, vb,
                       tfh, xh, inWt, qkvWt, qkvb, oWt, n);
  }
  hipLaunchKernelGGL(k_count, dim3((e + 255) / 256), dim3(b256), 0, stream, dst, deg, e);
  hipLaunchKernelGGL(k_scan_part, dim3(nb), dim3(b256), 0, stream, deg, bsum, n);
  hipLaunchKernelGGL(k_scan_mid, dim3(1), dim3(64), 0, stream, bsum, boff, nb);
  hipLaunchKernelGGL(k_scan_apply, dim3(nb), dim3(b256), 0, stream, deg, boff, row_ptr, cursor, n, e);
  hipLaunchKernelGGL(k_scatter, dim3((e + 255) / 256), dim3(b256), 0, stream, src, dst, row_ptr, cursor, colbuf, e);

  dim3 ggrid_h(HID / 64, (n + 127) / 128);
  dim3 ggrid_qkv(QKVW / 128, (n + 127) / 128);
  hipLaunchKernelGGL(k_gemm_f16, ggrid_h, dim3(b256), 0, stream,
                     xh, 32, xh, 32, inWt, inb, h, n, HID, 32, 0);

  int nchunks = (n + 63) / 64;
  for (int l = 0; l < NL; ++l) {
    const _Float16* qkvWtl = qkvWt + (size_t)l * QKVW * (HID + TD);
    const float*    qkvbl  = qkvb + (size_t)l * QKVW;
    const _Float16* oWtl   = oWt + (size_t)l * HID * HID;
    hipLaunchKernelGGL(k_gemm_qkv, ggrid_qkv, dim3(b256), 0, stream,
                       h, HID, tfh, TD, qkvWtl, qkvbl, Qbuf, KV, n, HID + TD);
    hipLaunchKernelGGL(k_attn, dim3(nchunks * 8), dim3(b256), 0, stream,
                       Qbuf, KV, row_ptr, colbuf, ao, n);
    hipLaunchKernelGGL(k_gemm_f16, ggrid_h, dim3(b256), 0, stream,
                       ao, HID, ao, HID, oWtl, ob + l * HID, h, n, HID, HID, 1);
  }

  hipLaunchKernelGGL(k_pool_partial, dim3(256), dim3(b256), 0, stream, h, partial, n);
  hipLaunchKernelGGL(k_final, dim3(1), dim3(b256), 0, stream, partial, c1W, c1b, c2W, c2b, (float*)d_out, n);
}

// Round 14
// 460.957 us; speedup vs baseline: 1.1740x; 1.0707x over previous
//
#include <hip/hip_runtime.h>
#include <math.h>

#define HID 256
#define TD 32
#define NL 3
#define C1DIM 128
#define OUTDIM 2
#define QKVW 768

using half8  = __attribute__((ext_vector_type(8))) _Float16;
using half4v = __attribute__((ext_vector_type(4))) _Float16;
using half2v = __attribute__((ext_vector_type(2))) _Float16;
using f32x4  = __attribute__((ext_vector_type(4))) float;

typedef __attribute__((address_space(1))) void gbl_void_t;
typedef __attribute__((address_space(3))) void lds_void_t;

__device__ __forceinline__ void load16_to_lds(const void* g, void* l) {
  __builtin_amdgcn_global_load_lds((const gbl_void_t*)g, (lds_void_t*)l, 16, 0, 0);
}

__device__ __forceinline__ float dot8h(half8 a, half8 b, float acc) {
#if __has_builtin(__builtin_amdgcn_fdot2)
  union { half8 v; half2v h2[4]; } ua, ub;
  ua.v = a; ub.v = b;
#pragma unroll
  for (int j = 0; j < 4; ++j) acc = __builtin_amdgcn_fdot2(ua.h2[j], ub.h2[j], acc, false);
  return acc;
#else
#pragma unroll
  for (int j = 0; j < 8; ++j) acc += (float)a[j] * (float)b[j];
  return acc;
#endif
}

// ---------- setup: ts min/max (single block) + zero deg ----------
__global__ __launch_bounds__(1024) void k_tsmm(const float* __restrict__ ts,
                                               float* __restrict__ mmf,
                                               int* __restrict__ deg, int n) {
  int t = threadIdx.x;
  float lmin = INFINITY, lmax = -INFINITY;
  for (int i = t; i < n; i += 1024) {
    float v = ts[i];
    lmin = fminf(lmin, v);
    lmax = fmaxf(lmax, v);
    deg[i] = 0;
  }
#pragma unroll
  for (int off = 32; off >= 1; off >>= 1) {
    lmin = fminf(lmin, __shfl_xor(lmin, off));
    lmax = fmaxf(lmax, __shfl_xor(lmax, off));
  }
  __shared__ float wmin[16], wmax[16];
  int lane = t & 63, w = t >> 6;
  if (lane == 0) { wmin[w] = lmin; wmax[w] = lmax; }
  __syncthreads();
  if (t == 0) {
    float a = INFINITY, b = -INFINITY;
    for (int i = 0; i < 16; ++i) { a = fminf(a, wmin[i]); b = fmaxf(b, wmax[i]); }
    mmf[0] = a; mmf[1] = b;
  }
}

// ---------- merged time encoding + x conversion ----------
__global__ void k_enc(const float* __restrict__ ts, const float* __restrict__ freq,
                      const float* __restrict__ mmf, const float* __restrict__ x,
                      _Float16* __restrict__ tfh, _Float16* __restrict__ xh, int n) {
  int idx = blockIdx.x * blockDim.x + threadIdx.x;
  int nt = n * TD;
  if (idx < nt) {
    int node = idx >> 5, j = idx & 31;
    float t = (ts[node] - mmf[0]) / (mmf[1] - mmf[0] + 1e-8f);
    float w = t * freq[j & 15];
    tfh[idx] = (_Float16)((j < 16) ? cosf(w) : sinf(w));
  } else if (idx < nt + n * 32) {
    int i2 = idx - nt;
    xh[i2] = (_Float16)x[i2];
  }
}

// ---------- merged weight prep (layers 1..2 qkv + all o transposes + biases) ----------
__global__ void k_prep(const float* __restrict__ qW,
                       const float* __restrict__ kW, const float* __restrict__ vW,
                       const float* __restrict__ oW, const float* __restrict__ qb,
                       const float* __restrict__ kb, const float* __restrict__ vb,
                       _Float16* __restrict__ qkvWt,
                       float* __restrict__ qkvb, _Float16* __restrict__ oWt) {
  int idx = blockIdx.x * blockDim.x + threadIdx.x;
  const int KQ = HID + TD;
  const int S1 = NL * QKVW * KQ;
  const int S2 = NL * QKVW;
  const int S3 = NL * HID * HID;
  if (idx < S1) {
    int l = idx / (QKVW * KQ);
    int rem = idx - l * (QKVW * KQ);
    int nrow = rem / KQ;
    int k = rem - nrow * KQ;
    float v;
    if (nrow < 256)      v = qW[(size_t)l * KQ * HID + (size_t)k * HID + nrow];
    else if (nrow < 512) v = kW[(size_t)l * KQ * HID + (size_t)k * HID + (nrow - 256)];
    else                 v = (k < HID) ? vW[(size_t)l * HID * HID + (size_t)k * HID + (nrow - 512)] : 0.f;
    qkvWt[idx] = (_Float16)v;
  } else if ((idx -= S1) < S2) {
    int l = idx / QKVW;
    int j = idx - l * QKVW;
    float v;
    if (j < 256)      v = qb[l * HID + j];
    else if (j < 512) v = kb[l * HID + (j - 256)];
    else              v = vb[l * HID + (j - 512)];
    qkvb[idx] = v;
  } else if ((idx -= S2) < S3) {
    int l = idx / (HID * HID);
    int rem = idx - l * (HID * HID);
    int nrow = rem / HID;
    int k = rem - nrow * HID;
    oWt[idx] = (_Float16)oW[(size_t)l * HID * HID + (size_t)k * HID + nrow];
  }
}

// ---------- layer-0 fold: WcT[768][64] = [inW@W0_h ; W0_tf]^T, bc = qkvb0 + inb@W0_h ----------
// j = idx/768 (0..64), nrow = idx%768. j<32: x-part dot; 32<=j<64: tf row copy; j==64: bias.
__global__ __launch_bounds__(256) void k_fold(const float* __restrict__ inW,
                                              const float* __restrict__ inb,
                                              const float* __restrict__ qW,
                                              const float* __restrict__ kW,
                                              const float* __restrict__ vW,
                                              const float* __restrict__ qb,
                                              const float* __restrict__ kb,
                                              const float* __restrict__ vb,
                                              _Float16* __restrict__ WcT,
                                              float* __restrict__ bc) {
  int idx = blockIdx.x * 256 + threadIdx.x;
  if (idx >= 65 * QKVW) return;
  int j = idx / QKVW;
  int nrow = idx - j * QKVW;
  const int KQ = HID + TD;
  auto W0 = [&](int c, int nr) -> float {
    if (nr < 256)      return qW[(size_t)c * HID + nr];
    else if (nr < 512) return kW[(size_t)c * HID + (nr - 256)];
    else               return vW[(size_t)c * HID + (nr - 512)];
  };
  if (j < 32) {
    float acc = 0.f;
    for (int c = 0; c < 256; ++c) acc += inW[j * HID + c] * W0(c, nrow);
    WcT[(size_t)nrow * 64 + j] = (_Float16)acc;
  } else if (j < 64) {
    int r = 256 + (j - 32);  // tf row in [256,288)
    float v = 0.f;
    if (nrow < 256)      v = qW[(size_t)r * HID + nrow];
    else if (nrow < 512) v = kW[(size_t)r * HID + (nrow - 256)];
    // v-part: tf rows don't feed V -> 0
    WcT[(size_t)nrow * 64 + j] = (_Float16)v;
  } else {
    float acc;
    if (nrow < 256)      acc = qb[nrow];
    else if (nrow < 512) acc = kb[nrow - 256];
    else                 acc = vb[nrow - 512];
    for (int c = 0; c < 256; ++c) acc += inb[c] * W0(c, nrow);
    bc[nrow] = acc;
  }
}

__global__ void k_count(const int* __restrict__ dst, int* deg, int e) {
  int i = blockIdx.x * blockDim.x + threadIdx.x;
  if (i < e) atomicAdd(&deg[dst[i]], 1);
}

// ---------- 3-kernel scan ----------
__global__ __launch_bounds__(256) void k_scan_part(const int* __restrict__ deg,
                                                   int* __restrict__ bsum, int n) {
  int t = threadIdx.x;
  int idx = blockIdx.x * 256 + t;
  int v = (idx < n) ? deg[idx] : 0;
  int lane = t & 63, w = t >> 6;
  int x = v;
#pragma unroll
  for (int off = 1; off < 64; off <<= 1) {
    int y = __shfl_up(x, off);
    if (lane >= off) x += y;
  }
  __shared__ int ws[4];
  if (lane == 63) ws[w] = x;
  __syncthreads();
  if (t == 0) bsum[blockIdx.x] = ws[0] + ws[1] + ws[2] + ws[3];
}

__global__ __launch_bounds__(64) void k_scan_mid(const int* __restrict__ bsum,
                                                 int* __restrict__ boff, int nb) {
  int lane = threadIdx.x;
  int carry = 0;
  for (int base = 0; base < nb; base += 64) {
    int i = base + lane;
    int v = (i < nb) ? bsum[i] : 0;
    int x = v;
#pragma unroll
    for (int off = 1; off < 64; off <<= 1) {
      int y = __shfl_up(x, off);
      if (lane >= off) x += y;
    }
    if (i < nb) boff[i] = carry + x - v;
    carry += __shfl(x, 63);
  }
}

__global__ __launch_bounds__(256) void k_scan_apply(const int* __restrict__ deg,
                                                    const int* __restrict__ boff,
                                                    int* __restrict__ row_ptr,
                                                    int* __restrict__ cursor, int n, int e) {
  int t = threadIdx.x;
  int idx = blockIdx.x * 256 + t;
  int v = (idx < n) ? deg[idx] : 0;
  int lane = t & 63, w = t >> 6;
  int x = v;
#pragma unroll
  for (int off = 1; off < 64; off <<= 1) {
    int y = __shfl_up(x, off);
    if (lane >= off) x += y;
  }
  __shared__ int ws[4];
  if (lane == 63) ws[w] = x;
  __syncthreads();
  int wpre = 0;
  for (int i = 0; i < w; ++i) wpre += ws[i];
  if (idx < n) {
    row_ptr[idx] = boff[blockIdx.x] + wpre + x - v;
    cursor[idx] = 0;
  }
  if (idx == 0) row_ptr[n] = e;
}

__global__ void k_scatter(const int* __restrict__ src, const int* __restrict__ dst,
                          const int* __restrict__ row_ptr, int* cursor,
                          int* __restrict__ colbuf, int e) {
  int i = blockIdx.x * blockDim.x + threadIdx.x;
  if (i >= e) return;
  int d = dst[i];
  int p = atomicAdd(&cursor[d], 1);
  colbuf[row_ptr[d] + p] = src[i];
}

// ---------- fp16 MFMA GEMM (128x64 tile, BK=32, 4 waves, double-buffered LDS) ----------
// mode 0: plain C write; mode 1: ELU C write; mode 2: QKV split write
// KV layout: KV[((h*M)+row)*64 + isV*32 + dim]  (_Float16; 128 B per (head,row))
__global__ __launch_bounds__(256) void k_gemm_f16(
    const _Float16* __restrict__ A1, int K1,
    const _Float16* __restrict__ A2, int K2,
    const _Float16* __restrict__ Bt,
    const float* __restrict__ bias,
    _Float16* __restrict__ C,
    _Float16* __restrict__ Qb,
    _Float16* __restrict__ KV,
    int M, int Ncols, int Ktot, int mode) {
  __shared__ half8 smem8[2 * 768];
  char* smem = (char*)smem8;
  const int tid = threadIdx.x;
  const int lane = tid & 63, wave = tid >> 6;
  const int wm = wave >> 1, wn = wave & 1;
  const int row0 = blockIdx.y * 128;
  const int col0 = blockIdx.x * 64;

  auto stage = [&](int buf, int k0) {
    char* sA = smem + buf * 12288;
    char* sB = sA + 8192;
#pragma unroll
    for (int i = 0; i < 2; ++i) {
      int kg = i * 2 + (wave >> 1);
      int row = (wave & 1) * 64 + lane;
      int grow = row0 + row; if (grow > M - 1) grow = M - 1;
      int k = k0 + kg * 8;
      const _Float16* src = (k < K1) ? (A1 + (size_t)grow * K1 + k)
                                     : (A2 + (size_t)grow * K2 + (k - K1));
      load16_to_lds(src, sA + (i * 256 + wave * 64) * 16);
    }
    {
      const _Float16* src = Bt + (size_t)(col0 + lane) * Ktot + k0 + wave * 8;
      load16_to_lds(src, sB + wave * 64 * 16);
    }
  };

  f32x4 acc[4][2];
#pragma unroll
  for (int mf = 0; mf < 4; ++mf)
#pragma unroll
    for (int nf = 0; nf < 2; ++nf) acc[mf][nf] = f32x4{0.f, 0.f, 0.f, 0.f};

  const int nsteps = Ktot >> 5;
  int cur = 0;
  stage(0, 0);
  __syncthreads();
  for (int st = 0; st < nsteps; ++st) {
    if (st + 1 < nsteps) stage(cur ^ 1, (st + 1) * 32);
    char* sA = smem + cur * 12288;
    char* sB = sA + 8192;
    half8 af[4], bf[2];
#pragma unroll
    for (int mf = 0; mf < 4; ++mf) {
      int slot = (lane >> 4) * 128 + wm * 64 + mf * 16 + (lane & 15);
      af[mf] = *(const half8*)(sA + slot * 16);
    }
#pragma unroll
    for (int nf = 0; nf < 2; ++nf) {
      int slot = (lane >> 4) * 64 + wn * 32 + nf * 16 + (lane & 15);
      bf[nf] = *(const half8*)(sB + slot * 16);
    }
#pragma unroll
    for (int mf = 0; mf < 4; ++mf)
#pragma unroll
      for (int nf = 0; nf < 2; ++nf)
        acc[mf][nf] = __builtin_amdgcn_mfma_f32_16x16x32_f16(af[mf], bf[nf], acc[mf][nf], 0, 0, 0);
    __syncthreads();
    cur ^= 1;
  }

  const int rbase = row0 + wm * 64 + (lane >> 4) * 4;
  const int cbase = col0 + wn * 32 + (lane & 15);
#pragma unroll
  for (int nf = 0; nf < 2; ++nf) {
    int col = cbase + nf * 16;
    float bv = bias[col];
    if (mode != 2) {
#pragma unroll
      for (int mf = 0; mf < 4; ++mf) {
#pragma unroll
        for (int r = 0; r < 4; ++r) {
          int row = rbase + mf * 16 + r;
          if (row < M) {
            float v = acc[mf][nf][r] + bv;
            if (mode == 1) v = (v > 0.f) ? v : expm1f(v);
            C[(size_t)row * Ncols + col] = (_Float16)v;
          }
        }
      }
    } else {
      bool isQ = col < 256;
      int cc = col - 256;
      int isV = cc >> 8;          // 0 = K, 1 = V (when !isQ)
      int c2 = cc & 255;
      int hh = c2 >> 5, dim = c2 & 31;
      size_t kvoff = ((size_t)hh * M) * 64 + isV * 32 + dim;
#pragma unroll
      for (int mf = 0; mf < 4; ++mf) {
#pragma unroll
        for (int r = 0; r < 4; ++r) {
          int row = rbase + mf * 16 + r;
          if (row < M) {
            float v = acc[mf][nf][r] + bv;
            if (isQ) Qb[(size_t)row * HID + col] = (_Float16)v;
            else     KV[kvoff + (size_t)row * 64] = (_Float16)v;
          }
        }
      }
    }
  }
}

// ---------- attention: head-split (L2-resident), fp16 K/V, 4 threads/node ----------
// head = blockIdx.x & 7 (XCD round-robin); 64 nodes/block, 4 threads/node (8 dims each)
__global__ __launch_bounds__(256) void k_attn(const _Float16* __restrict__ Qb,
                                              const _Float16* __restrict__ KV,
                                              const int* __restrict__ row_ptr,
                                              const int* __restrict__ colbuf,
                                              _Float16* __restrict__ out, int n) {
  int h = blockIdx.x & 7;
  int node = (blockIdx.x >> 3) * 64 + (threadIdx.x >> 2);
  if (node >= n) return;
  int j = threadIdx.x & 3;   // dims j*8 .. j*8+7
  const float scale = 0.17677669529663687f;  // 1/sqrt(32)
  const _Float16* KVh = KV + ((size_t)h * n) * 64;

  half8 qh = *(const half8*)(Qb + (size_t)node * HID + h * 32 + j * 8);
  half8 qs;
#pragma unroll
  for (int q = 0; q < 8; ++q) qs[q] = (_Float16)((float)qh[q] * scale);

  int beg = row_ptr[node], end = row_ptr[node + 1];
  float m = -INFINITY, s = 0.f;
  float a[8] = {0.f, 0.f, 0.f, 0.f, 0.f, 0.f, 0.f, 0.f};

  for (int i = beg; i < end; i += 4) {
    half8 kk[4], vv[4];
#pragma unroll
    for (int t = 0; t < 4; ++t) {
      int ii = i + t; if (ii > end - 1) ii = end - 1;
      int sn = colbuf[ii];
      const _Float16* b = KVh + ((size_t)sn) * 64 + j * 8;
      kk[t] = *(const half8*)(b);
      vv[t] = *(const half8*)(b + 32);
    }
    float p[4];
#pragma unroll
    for (int t = 0; t < 4; ++t) p[t] = dot8h(qs, kk[t], 0.f);
#pragma unroll
    for (int t = 0; t < 4; ++t) {
      p[t] += __shfl_xor(p[t], 1);
      p[t] += __shfl_xor(p[t], 2);
      if (i + t >= end) p[t] = -INFINITY;  // tail mask (t=0 always real)
    }
#pragma unroll
    for (int t = 0; t < 4; ++t) {
      float sc_ = p[t];
      if (sc_ <= m) {
        float e2 = __expf(sc_ - m);
        s += e2;
#pragma unroll
        for (int q = 0; q < 8; ++q) a[q] = fmaf(e2, (float)vv[t][q], a[q]);
      } else {
        float f = __expf(m - sc_);  // m=-inf on first real edge -> f=0
        s = s * f + 1.f;
#pragma unroll
        for (int q = 0; q < 8; ++q) a[q] = fmaf(a[q], f, (float)vv[t][q]);
        m = sc_;
      }
    }
  }

  float inv = (s > 0.f) ? (1.f / s) : 0.f;
  half8 o;
#pragma unroll
  for (int q = 0; q < 8; ++q) o[q] = (_Float16)(a[q] * inv);
  *(half8*)(out + (size_t)node * HID + h * 32 + j * 8) = o;
}

// ---------- pooling + classifier ----------
__global__ __launch_bounds__(256) void k_pool_partial(const _Float16* __restrict__ h,
                                                      float* __restrict__ partial, int n) {
  int b = blockIdx.x, t = threadIdx.x;
  float s = 0.f;
  for (int r = b; r < n; r += 256) s += (float)h[(size_t)r * HID + t];
  partial[b * HID + t] = s;
}

__global__ __launch_bounds__(256) void k_final(const float* __restrict__ partial,
                                               const float* __restrict__ c1W,
                                               const float* __restrict__ c1b,
                                               const float* __restrict__ c2W,
                                               const float* __restrict__ c2b,
                                               float* __restrict__ out, int n) {
  __shared__ float gl[HID];
  __shared__ float r1[C1DIM];
  int t = threadIdx.x;
  float s = 0.f;
  for (int b = 0; b < 256; b++) s += partial[b * HID + t];
  gl[t] = s / (float)n;
  __syncthreads();
  if (t < C1DIM) {
    float a = c1b[t];
    for (int k = 0; k < HID; k++) a += gl[k] * c1W[k * C1DIM + t];
    r1[t] = fmaxf(a, 0.f);
  }
  __syncthreads();
  if (t < OUTDIM) {
    float a = c2b[t];
    for (int k = 0; k < C1DIM; k++) a += r1[k] * c2W[k * OUTDIM + t];
    out[t] = a;
  }
}

// ---------- host launcher ----------
extern "C" void kernel_launch(void* const* d_in, const int* in_sizes, int n_in,
                              void* d_out, int out_size, void* d_ws, size_t ws_size,
                              hipStream_t stream) {
  const float* x    = (const float*)d_in[0];
  const float* ts   = (const float*)d_in[1];
  const int*   ei   = (const int*)d_in[2];
  const float* freq = (const float*)d_in[4];
  const float* inW  = (const float*)d_in[5];
  const float* inb  = (const float*)d_in[6];
  const float* qW   = (const float*)d_in[7];
  const float* qb   = (const float*)d_in[8];
  const float* kW   = (const float*)d_in[9];
  const float* kb   = (const float*)d_in[10];
  const float* vW   = (const float*)d_in[11];
  const float* vb   = (const float*)d_in[12];
  const float* oW   = (const float*)d_in[13];
  const float* ob   = (const float*)d_in[14];
  const float* c1W  = (const float*)d_in[15];
  const float* c1b  = (const float*)d_in[16];
  const float* c2W  = (const float*)d_in[17];
  const float* c2b  = (const float*)d_in[18];

  int n = in_sizes[1];
  int e = in_sizes[2] / 2;
  const int* src = ei;
  const int* dst = ei + e;
  int nb = (n + 255) / 256;

  char* w = (char*)d_ws;
  size_t off = 0;
  auto alloc = [&](size_t bytes) -> char* {
    char* p = w + off;
    off = (off + bytes + 255) & ~(size_t)255;
    return p;
  };
  _Float16* tfh     = (_Float16*)alloc((size_t)n * TD * 2);
  _Float16* xh      = (_Float16*)alloc((size_t)n * 32 * 2);
  _Float16* h       = (_Float16*)alloc((size_t)n * HID * 2);
  _Float16* Qbuf    = (_Float16*)alloc((size_t)n * HID * 2);
  _Float16* KV      = (_Float16*)alloc((size_t)n * 512 * 2);  // 8 heads x 64 halves
  _Float16* ao      = (_Float16*)alloc((size_t)n * HID * 2);
  _Float16* qkvWt   = (_Float16*)alloc((size_t)NL * QKVW * (HID + TD) * 2);
  float*    qkvb    = (float*)alloc((size_t)NL * QKVW * 4);
  _Float16* oWt     = (_Float16*)alloc((size_t)NL * HID * HID * 2);
  _Float16* WcT     = (_Float16*)alloc((size_t)QKVW * 64 * 2);
  float*    bc      = (float*)alloc((size_t)QKVW * 4);
  int*      deg     = (int*)alloc((size_t)n * 4);
  int*      cursor  = (int*)alloc((size_t)n * 4);
  int*      row_ptr = (int*)alloc((size_t)(n + 1) * 4);
  int*      colbuf  = (int*)alloc((size_t)e * 4);
  int*      bsum    = (int*)alloc((size_t)nb * 4);
  int*      boff    = (int*)alloc((size_t)nb * 4);
  float*    partial = (float*)alloc((size_t)256 * HID * 4);
  float*    mmf     = (float*)alloc(256);

  int b256 = 256;
  hipLaunchKernelGGL(k_tsmm, dim3(1), dim3(1024), 0, stream, ts, mmf, deg, n);
  hipLaunchKernelGGL(k_enc, dim3((n * 64 + 255) / 256), dim3(b256), 0, stream,
                     ts, freq, mmf, x, tfh, xh, n);
  {
    int total = NL * QKVW * (HID + TD) + NL * QKVW + NL * HID * HID;
    hipLaunchKernelGGL(k_prep, dim3((total + 255) / 256), dim3(b256), 0, stream,
                       qW, kW, vW, oW, qb, kb, vb, qkvWt, qkvb, oWt);
  }
  hipLaunchKernelGGL(k_fold, dim3((65 * QKVW + 255) / 256), dim3(b256), 0, stream,
                     inW, inb, qW, kW, vW, qb, kb, vb, WcT, bc);
  hipLaunchKernelGGL(k_count, dim3((e + 255) / 256), dim3(b256), 0, stream, dst, deg, e);
  hipLaunchKernelGGL(k_scan_part, dim3(nb), dim3(b256), 0, stream, deg, bsum, n);
  hipLaunchKernelGGL(k_scan_mid, dim3(1), dim3(64), 0, stream, bsum, boff, nb);
  hipLaunchKernelGGL(k_scan_apply, dim3(nb), dim3(b256), 0, stream, deg, boff, row_ptr, cursor, n, e);
  hipLaunchKernelGGL(k_scatter, dim3((e + 255) / 256), dim3(b256), 0, stream, src, dst, row_ptr, cursor, colbuf, e);

  dim3 ggrid_h(HID / 64, (n + 127) / 128);
  dim3 ggrid_qkv(QKVW / 64, (n + 127) / 128);
  int nchunks = (n + 63) / 64;
  for (int l = 0; l < NL; ++l) {
    const float*    qkvbl  = qkvb + (size_t)l * QKVW;
    const _Float16* oWtl   = oWt + (size_t)l * HID * HID;
    if (l == 0) {
      // folded: QKV0 = [x, tf] @ Wc + bc   (K = 64)
      hipLaunchKernelGGL(k_gemm_f16, ggrid_qkv, dim3(b256), 0, stream,
                         xh, 32, tfh, 32, WcT, bc, (_Float16*)nullptr, Qbuf, KV,
                         n, QKVW, 64, 2);
    } else {
      const _Float16* qkvWtl = qkvWt + (size_t)l * QKVW * (HID + TD);
      hipLaunchKernelGGL(k_gemm_f16, ggrid_qkv, dim3(b256), 0, stream,
                         h, HID, tfh, TD, qkvWtl, qkvbl, (_Float16*)nullptr, Qbuf, KV,
                         n, QKVW, HID + TD, 2);
    }
    hipLaunchKernelGGL(k_attn, dim3(nchunks * 8), dim3(b256), 0, stream,
                       Qbuf, KV, row_ptr, colbuf, ao, n);
    hipLaunchKernelGGL(k_gemm_f16, ggrid_h, dim3(b256), 0, stream,
                       ao, HID, ao, HID, oWtl, ob + l * HID, h, (_Float16*)nullptr, (_Float16*)nullptr,
                       n, HID, HID, 1);
  }

  hipLaunchKernelGGL(k_pool_partial, dim3(256), dim3(b256), 0, stream, h, partial, n);
  hipLaunchKernelGGL(k_final, dim3(1), dim3(b256), 0, stream, partial, c1W, c1b, c2W, c2b, (float*)d_out, n);
}